// Round 5
// baseline (64.302 us; speedup 1.0000x reference)
//
#include <hip/hip_runtime.h>

// CAM: out = (q @ k^T) @ v + v  ==  q @ (k^T @ v) + v.   S[b] = k^T v is 49x49.
//   ktv : partial S per (batch,split). K rows via SGPR broadcast (s_load),
//         V coalesced per lane. [R2-proven. Uniform-address LDS reads are NOT
//         a cheap broadcast (R3: 5x regression) — broadcast must use s_load.]
//   sred: sum split partials -> padded S[49][52] per batch.
//   qs  : thread = output row. q staged coalesced->LDS, read per-lane (full
//         bank parallelism); S rows wave-uniform -> s_load/SGPR; acc in VGPRs;
//         epilogue transposes through LDS for coalesced store. [Replaces the
//         uniform-ds_read_b128 variant that was LDS-return-BW bound at 41us.]

#define BATCH  128
#define CH     1024
#define NN     49
#define NPAD   52
#define SPLITB 4
#define WAVES_K 8                          // ktv: 512 threads = 8 waves
#define CCHUNK (CH / (SPLITB * WAVES_K))   // 32 channels per wave

// ---------------- Kernel 1: Spart[b*SPLITB+s] = K-chunk^T @ V-chunk ---------
__global__ __launch_bounds__(512) void ktv_kernel(
    const float* __restrict__ Kg, const float* __restrict__ Vg,
    float* __restrict__ Spart) {
  const int blk = blockIdx.x;
  const int b   = blk / SPLITB;
  const int s   = blk - b * SPLITB;
  const int tid = threadIdx.x;
  const int wv  = __builtin_amdgcn_readfirstlane(tid >> 6);
  const int lane = tid & 63;
  const bool act = lane < NN;

  const float* Kb = Kg + (size_t)b * CH * NN;
  const float* Vb = Vg + (size_t)b * CH * NN;
  const int c0 = s * (CH / SPLITB) + wv * CCHUNK;

  float acc[NN];
  #pragma unroll
  for (int i = 0; i < NN; ++i) acc[i] = 0.f;

  #pragma unroll 2
  for (int cc = 0; cc < CCHUNK; ++cc) {
    const int c = c0 + cc;
    const float* kr = Kb + (size_t)c * NN;     // wave-uniform -> s_load
    const float vj = act ? Vb[(size_t)c * NN + lane] : 0.f;  // coalesced
    #pragma unroll
    for (int i = 0; i < NN; ++i) acc[i] = fmaf(kr[i], vj, acc[i]);
  }

  // reduce 8 wave-partials (4 LDS buffers, waves 4-7 add into 0-3)
  __shared__ float red[4][NN * 64];
  if (wv < 4) {
    #pragma unroll
    for (int i = 0; i < NN; ++i) red[wv][i * 64 + lane] = acc[i];
  }
  __syncthreads();
  if (wv >= 4) {
    #pragma unroll
    for (int i = 0; i < NN; ++i) red[wv - 4][i * 64 + lane] += acc[i];
  }
  __syncthreads();

  float* Sp = Spart + (size_t)blk * (NN * NN);
  for (int e = tid; e < NN * NN; e += 512) {
    const int i = e / NN, j = e - i * NN;
    Sp[e] = (red[0][i * 64 + j] + red[1][i * 64 + j]) +
            (red[2][i * 64 + j] + red[3][i * 64 + j]);
  }
}

// ---------------- Kernel 2: S[b] = sum_s Spart, padded to 49x52 -------------
__global__ __launch_bounds__(256) void sred_kernel(
    const float* __restrict__ Spart, float* __restrict__ Sg) {
  const int b = blockIdx.x;
  const int t = threadIdx.x;
  for (int e = t; e < NN * NPAD; e += 256) {
    const int m = e / NPAD, n = e - m * NPAD;
    float v = 0.f;
    if (n < NN) {
      #pragma unroll
      for (int s = 0; s < SPLITB; ++s)
        v += Spart[(size_t)(b * SPLITB + s) * (NN * NN) + m * NN + n];
    }
    Sg[(size_t)b * (NN * NPAD) + e] = v;
  }
}

// ---------------- Kernel 3: out[b,r,:] = q[b,r,:] @ S[b] + v[b,r,:] ---------
// thread = row. q: coalesced->LDS->per-lane b128. S rows: s_load (SGPR).
#define QBLK 256      // rows per block == threads per block

__global__ __launch_bounds__(256) void qs_kernel(
    const float* __restrict__ Qg, const float* __restrict__ Vg,
    const float* __restrict__ Sg, float* __restrict__ Og) {
  const int blk = blockIdx.x;          // 512 blocks: 4 per batch
  const int b   = blk >> 2;
  const int rb  = blk & 3;
  const int tid = threadIdx.x;

  __shared__ __align__(16) float T[QBLK * NPAD];   // 53.2 KB -> 2 blocks/CU

  const size_t base = ((size_t)b * CH + (size_t)rb * QBLK) * NN;

  // stage 256 q-rows into LDS, coalesced; incremental div/mod by 49
  {
    int idx = tid;
    int r = tid / 49, m = tid - (tid / 49) * 49;
    #pragma unroll 7
    for (int it = 0; it < 49; ++it) {
      T[r * NPAD + m] = Qg[base + idx];
      idx += QBLK;
      r += 5; m += 11;                  // +256 = +5*49 + 11
      const int ge = (m >= 49);
      m = ge ? m - 49 : m;
      r = ge ? r + 1 : r;
    }
  }
  __syncthreads();

  const float* __restrict__ Sb = Sg + (size_t)b * (NN * NPAD);
  const float* tq = &T[tid * NPAD];    // own row: per-lane distinct reads

  float acc[NN];
  #pragma unroll
  for (int n = 0; n < NN; ++n) acc[n] = 0.f;

  for (int g = 0; g < 12; ++g) {       // runtime loop; inner fully unrolled
    const float4 qv = *(const float4*)&tq[4 * g];     // 1 ds_read_b128
    const float* s0 = Sb + (4 * g + 0) * NPAD;        // uniform -> s_load
    const float* s1 = Sb + (4 * g + 1) * NPAD;
    const float* s2 = Sb + (4 * g + 2) * NPAD;
    const float* s3 = Sb + (4 * g + 3) * NPAD;
    #pragma unroll
    for (int n = 0; n < NN; ++n) acc[n] = fmaf(qv.x, s0[n], acc[n]);
    #pragma unroll
    for (int n = 0; n < NN; ++n) acc[n] = fmaf(qv.y, s1[n], acc[n]);
    #pragma unroll
    for (int n = 0; n < NN; ++n) acc[n] = fmaf(qv.z, s2[n], acc[n]);
    #pragma unroll
    for (int n = 0; n < NN; ++n) acc[n] = fmaf(qv.w, s3[n], acc[n]);
  }
  {                                    // tail m = 48
    const float qm = tq[48];
    const float* s48 = Sb + 48 * NPAD;
    #pragma unroll
    for (int n = 0; n < NN; ++n) acc[n] = fmaf(qm, s48[n], acc[n]);
  }

  // write acc to own LDS row (only this thread ever touches row tid)
  float* tw = &T[tid * NPAD];
  #pragma unroll
  for (int n = 0; n < 48; n += 4)
    *(float4*)&tw[n] = make_float4(acc[n], acc[n + 1], acc[n + 2], acc[n + 3]);
  tw[48] = acc[48];
  __syncthreads();

  // coalesced store with v-add
  {
    int idx = tid;
    int r = tid / 49, m = tid - (tid / 49) * 49;
    #pragma unroll 7
    for (int it = 0; it < 49; ++it) {
      Og[base + idx] = T[r * NPAD + m] + Vg[base + idx];
      idx += QBLK;
      r += 5; m += 11;
      const int ge = (m >= 49);
      m = ge ? m - 49 : m;
      r = ge ? r + 1 : r;
    }
  }
}

extern "C" void kernel_launch(void* const* d_in, const int* in_sizes, int n_in,
                              void* d_out, int out_size, void* d_ws, size_t ws_size,
                              hipStream_t stream) {
  (void)in_sizes; (void)n_in; (void)out_size; (void)ws_size;
  const float* v1 = (const float*)d_in[0];
  const float* q1 = (const float*)d_in[1];
  const float* k1 = (const float*)d_in[2];
  float* out = (float*)d_out;

  float* spart = (float*)d_ws;                                 // 512*2401*4 = 4.92 MB
  float* sg    = spart + (size_t)BATCH * SPLITB * NN * NN;     // 128*49*52*4 = 1.30 MB

  ktv_kernel<<<dim3(BATCH * SPLITB), dim3(512), 0, stream>>>(k1, v1, spart);
  sred_kernel<<<dim3(BATCH), dim3(256), 0, stream>>>(spart, sg);
  qs_kernel<<<dim3(BATCH * 4), dim3(QBLK), 0, stream>>>(q1, v1, sg, out);
}

// Round 6
// 62.126 us; speedup vs baseline: 1.0350x; 1.0350x over previous
//
#include <hip/hip_runtime.h>

// CAM: out = (q @ k^T) @ v + v  ==  q @ (k^T @ v) + v.   S[b] = k^T v is 49x49.
//   ktv : MFMA (bf16 hi/lo compensated split, 3 mfma per chunk). K,V staged
//         transposed in LDS (stride 65 f32, conflict-free). Replaces the
//         s_load-broadcast version (43us: scalar path streaming 25MB from HBM
//         is latency-serialized; lgkmcnt(0) drains per channel).
//   sred: sum split partials -> padded S[49][52] per batch.
//   qs  : thread = output row. q coalesced->LDS->per-lane; S rows via s_load
//         (L2-resident, reused CH times -> scalar path OK here). [R5 version]

#define BATCH  128
#define CH     1024
#define NN     49
#define NPAD   52
#define SPLITB 4
#define KCHB   (CH / SPLITB)   // 256 channels per ktv block
#define SCH    64              // channels per LDS super-chunk
#define LDK    65              // f32 stride of transposed LDS tiles

typedef short  bf16x8 __attribute__((ext_vector_type(8)));
typedef float  f32x16 __attribute__((ext_vector_type(16)));

__device__ __forceinline__ short bf16_trunc(float x) {
  return (short)(__builtin_bit_cast(unsigned, x) >> 16);
}
__device__ __forceinline__ float bf16_f32(short h) {
  return __builtin_bit_cast(float, ((unsigned)(unsigned short)h) << 16);
}

// ---------------- Kernel 1: Spart[b*SPLITB+s] = K-chunk^T @ V-chunk ---------
__global__ __launch_bounds__(256) void ktv_kernel(
    const float* __restrict__ Kg, const float* __restrict__ Vg,
    float* __restrict__ Spart) {
  const int blk  = blockIdx.x;
  const int b    = blk >> 2;
  const int s    = blk & 3;
  const int tid  = threadIdx.x;
  const int wv   = tid >> 6;
  const int lane = tid & 63;
  const int g    = lane >> 5;          // lane-half (k-group select)
  const int ln   = lane & 31;          // m/n within 32x32 tile
  const int i0   = (wv >> 1) * 32;     // S-row quadrant base
  const int j0   = (wv & 1)  * 32;     // S-col quadrant base

  __shared__ float Kt[64 * LDK];       // Kt[n][c] = K[c][n], rows 49..63 zero
  __shared__ float Vt[64 * LDK];

  // zero pad rows 49..63 (contiguous tail), done once; staging never touches
  for (int e = tid; e < 15 * LDK; e += 256) {
    Kt[NN * LDK + e] = 0.f;
    Vt[NN * LDK + e] = 0.f;
  }

  f32x16 acc;
  #pragma unroll
  for (int r = 0; r < 16; ++r) acc[r] = 0.f;

  const size_t cbase = ((size_t)b * CH + (size_t)s * KCHB) * NN;

  for (int sc = 0; sc < KCHB / SCH; ++sc) {     // 4 super-chunks of 64 ch
    __syncthreads();                            // protect prior reads
    const float* Ksrc = Kg + cbase + (size_t)sc * SCH * NN;
    const float* Vsrc = Vg + cbase + (size_t)sc * SCH * NN;
    for (int idx = tid; idx < SCH * NN; idx += 256) {   // coalesced stage
      const int c = idx / NN, n = idx - c * NN;
      Kt[n * LDK + c] = Ksrc[idx];              // transposed scatter
      Vt[n * LDK + c] = Vsrc[idx];              // bank = (n + c) % 32: ok
    }
    __syncthreads();

    #pragma unroll
    for (int kc = 0; kc < SCH / 16; ++kc) {     // 16-channel MFMA chunks
      const int cb = kc * 16 + g * 8;           // lane's 8 channels
      const float* ka = &Kt[(i0 + ln) * LDK + cb];   // conflict-free reads
      const float* vb = &Vt[(j0 + ln) * LDK + cb];
      bf16x8 ah, al, bh, bl;
      #pragma unroll
      for (int e = 0; e < 8; ++e) {
        // A and B use the IDENTICAL per-lane channel formula -> any k-slot
        // permutation assumption cancels (channel sum is order-invariant).
        const float kx = ka[e], vx = vb[e];
        const short kh = bf16_trunc(kx);
        const short vh = bf16_trunc(vx);
        ah[e] = kh;  al[e] = bf16_trunc(kx - bf16_f32(kh));
        bh[e] = vh;  bl[e] = bf16_trunc(vx - bf16_f32(vh));
      }
      acc = __builtin_amdgcn_mfma_f32_32x32x16_bf16(ah, bh, acc, 0, 0, 0);
      acc = __builtin_amdgcn_mfma_f32_32x32x16_bf16(ah, bl, acc, 0, 0, 0);
      acc = __builtin_amdgcn_mfma_f32_32x32x16_bf16(al, bh, acc, 0, 0, 0);
    }
  }

  // C/D layout (HW-verified m74/m101): col = lane&31, row = (r&3)+8*(r>>2)+4*(lane>>5)
  float* Sp = Spart + (size_t)blk * (NN * NN);
  const int j = j0 + ln;
  if (j < NN) {
    #pragma unroll
    for (int r = 0; r < 16; ++r) {
      const int i = i0 + (r & 3) + 8 * (r >> 2) + 4 * g;
      if (i < NN) Sp[i * NN + j] = acc[r];
    }
  }
}

// ---------------- Kernel 2: S[b] = sum_s Spart, padded to 49x52 -------------
__global__ __launch_bounds__(256) void sred_kernel(
    const float* __restrict__ Spart, float* __restrict__ Sg) {
  const int b = blockIdx.x;
  const int t = threadIdx.x;
  for (int e = t; e < NN * NPAD; e += 256) {
    const int m = e / NPAD, n = e - m * NPAD;
    float v = 0.f;
    if (n < NN) {
      #pragma unroll
      for (int s = 0; s < SPLITB; ++s)
        v += Spart[(size_t)(b * SPLITB + s) * (NN * NN) + m * NN + n];
    }
    Sg[(size_t)b * (NN * NPAD) + e] = v;
  }
}

// ---------------- Kernel 3: out[b,r,:] = q[b,r,:] @ S[b] + v[b,r,:] ---------
// thread = row. q: coalesced->LDS->per-lane b128. S rows: s_load (SGPR).
#define QBLK 256      // rows per block == threads per block

__global__ __launch_bounds__(256) void qs_kernel(
    const float* __restrict__ Qg, const float* __restrict__ Vg,
    const float* __restrict__ Sg, float* __restrict__ Og) {
  const int blk = blockIdx.x;          // 512 blocks: 4 per batch
  const int b   = blk >> 2;
  const int rb  = blk & 3;
  const int tid = threadIdx.x;

  __shared__ __align__(16) float T[QBLK * NPAD];   // 53.2 KB -> 2 blocks/CU

  const size_t base = ((size_t)b * CH + (size_t)rb * QBLK) * NN;

  // stage 256 q-rows into LDS, coalesced; incremental div/mod by 49
  {
    int idx = tid;
    int r = tid / 49, m = tid - (tid / 49) * 49;
    #pragma unroll 7
    for (int it = 0; it < 49; ++it) {
      T[r * NPAD + m] = Qg[base + idx];
      idx += QBLK;
      r += 5; m += 11;                  // +256 = +5*49 + 11
      const int ge = (m >= 49);
      m = ge ? m - 49 : m;
      r = ge ? r + 1 : r;
    }
  }
  __syncthreads();

  const float* __restrict__ Sb = Sg + (size_t)b * (NN * NPAD);
  const float* tq = &T[tid * NPAD];    // own row: per-lane distinct reads

  float acc[NN];
  #pragma unroll
  for (int n = 0; n < NN; ++n) acc[n] = 0.f;

  for (int g = 0; g < 12; ++g) {       // runtime loop; inner fully unrolled
    const float4 qv = *(const float4*)&tq[4 * g];     // 1 ds_read_b128
    const float* s0 = Sb + (4 * g + 0) * NPAD;        // uniform -> s_load
    const float* s1 = Sb + (4 * g + 1) * NPAD;
    const float* s2 = Sb + (4 * g + 2) * NPAD;
    const float* s3 = Sb + (4 * g + 3) * NPAD;
    #pragma unroll
    for (int n = 0; n < NN; ++n) acc[n] = fmaf(qv.x, s0[n], acc[n]);
    #pragma unroll
    for (int n = 0; n < NN; ++n) acc[n] = fmaf(qv.y, s1[n], acc[n]);
    #pragma unroll
    for (int n = 0; n < NN; ++n) acc[n] = fmaf(qv.z, s2[n], acc[n]);
    #pragma unroll
    for (int n = 0; n < NN; ++n) acc[n] = fmaf(qv.w, s3[n], acc[n]);
  }
  {                                    // tail m = 48
    const float qm = tq[48];
    const float* s48 = Sb + 48 * NPAD;
    #pragma unroll
    for (int n = 0; n < NN; ++n) acc[n] = fmaf(qm, s48[n], acc[n]);
  }

  // write acc to own LDS row (only this thread ever touches row tid)
  float* tw = &T[tid * NPAD];
  #pragma unroll
  for (int n = 0; n < 48; n += 4)
    *(float4*)&tw[n] = make_float4(acc[n], acc[n + 1], acc[n + 2], acc[n + 3]);
  tw[48] = acc[48];
  __syncthreads();

  // coalesced store with v-add
  {
    int idx = tid;
    int r = tid / 49, m = tid - (tid / 49) * 49;
    #pragma unroll 7
    for (int it = 0; it < 49; ++it) {
      Og[base + idx] = T[r * NPAD + m] + Vg[base + idx];
      idx += QBLK;
      r += 5; m += 11;
      const int ge = (m >= 49);
      m = ge ? m - 49 : m;
      r = ge ? r + 1 : r;
    }
  }
}

extern "C" void kernel_launch(void* const* d_in, const int* in_sizes, int n_in,
                              void* d_out, int out_size, void* d_ws, size_t ws_size,
                              hipStream_t stream) {
  (void)in_sizes; (void)n_in; (void)out_size; (void)ws_size;
  const float* v1 = (const float*)d_in[0];
  const float* q1 = (const float*)d_in[1];
  const float* k1 = (const float*)d_in[2];
  float* out = (float*)d_out;

  float* spart = (float*)d_ws;                                 // 512*2401*4 = 4.92 MB
  float* sg    = spart + (size_t)BATCH * SPLITB * NN * NN;     // 128*49*52*4 = 1.30 MB

  ktv_kernel<<<dim3(BATCH * SPLITB), dim3(256), 0, stream>>>(k1, v1, spart);
  sred_kernel<<<dim3(BATCH), dim3(256), 0, stream>>>(spart, sg);
  qs_kernel<<<dim3(BATCH * 4), dim3(QBLK), 0, stream>>>(q1, v1, sg, out);
}

// Round 7
// 52.216 us; speedup vs baseline: 1.2315x; 1.1898x over previous
//
#include <hip/hip_runtime.h>

// CAM: out = (q @ k^T) @ v + v  ==  q @ (k^T @ v) + v.   S[b] = k^T v is 49x49.
// All-MFMA, barrier-light:
//   ktv : NO LDS. A[i][c]=K[c][i], B[c][j]=V[c][j] both read as lane-
//         consecutive coalesced global loads; zero barriers -> compiler
//         pipelines loads across the whole K-loop. bf16 hi/lo x3 MFMA.
//   sred: sum split partials -> zero-padded S[64][52] per batch.
//   qs  : A=q via small LDS transpose (16.6KB), B=S coalesced global (L2-hot),
//         D = 64x49 out tile + v, coalesced stores. Same hi/lo x3 MFMA.
// R6 validated the A/B fill convention + C/D mapping (same formulas reused).

#define BATCH  128
#define CH     1024
#define NN     49
#define NPAD   52
#define LDQ    65

typedef short  bf16x8 __attribute__((ext_vector_type(8)));
typedef float  f32x16 __attribute__((ext_vector_type(16)));

__device__ __forceinline__ short bf16_trunc(float x) {
  return (short)(__builtin_bit_cast(unsigned, x) >> 16);
}
__device__ __forceinline__ float bf16_f32(short h) {
  return __builtin_bit_cast(float, ((unsigned)(unsigned short)h) << 16);
}

// ---------------- Kernel 1: Spart[b*split+s] = K-chunk^T @ V-chunk ----------
__global__ __launch_bounds__(256) void ktv_kernel(
    const float* __restrict__ Kg, const float* __restrict__ Vg,
    float* __restrict__ Spart, int split, int nchunks) {
  const int blk  = blockIdx.x;
  const int b    = blk / split;
  const int s    = blk - b * split;
  const int tid  = threadIdx.x;
  const int wv   = tid >> 6;
  const int lane = tid & 63;
  const int g    = lane >> 5;
  const int ln   = lane & 31;
  const int i0   = (wv >> 1) * 32;
  const int j0   = (wv & 1)  * 32;
  const int rowA = min(i0 + ln, NN - 1);   // clamped: garbage -> discarded rows
  const int rowB = min(j0 + ln, NN - 1);

  const size_t cbase = ((size_t)b * CH + (size_t)s * (nchunks * 16)) * NN;
  const float* Ka = Kg + cbase + (size_t)(g * 8) * NN + rowA;
  const float* Vb = Vg + cbase + (size_t)(g * 8) * NN + rowB;

  f32x16 acc;
  #pragma unroll
  for (int r = 0; r < 16; ++r) acc[r] = 0.f;

  #pragma unroll 2
  for (int kc = 0; kc < nchunks; ++kc) {
    const float* ka = Ka + (size_t)kc * 16 * NN;
    const float* vb = Vb + (size_t)kc * 16 * NN;
    float kx[8], vx[8];
    #pragma unroll
    for (int e = 0; e < 8; ++e) { kx[e] = ka[e * NN]; vx[e] = vb[e * NN]; }
    bf16x8 ah, al, bh, bl;
    #pragma unroll
    for (int e = 0; e < 8; ++e) {
      const short kh = bf16_trunc(kx[e]);
      const short vh = bf16_trunc(vx[e]);
      ah[e] = kh;  al[e] = bf16_trunc(kx[e] - bf16_f32(kh));
      bh[e] = vh;  bl[e] = bf16_trunc(vx[e] - bf16_f32(vh));
    }
    acc = __builtin_amdgcn_mfma_f32_32x32x16_bf16(ah, bh, acc, 0, 0, 0);
    acc = __builtin_amdgcn_mfma_f32_32x32x16_bf16(ah, bl, acc, 0, 0, 0);
    acc = __builtin_amdgcn_mfma_f32_32x32x16_bf16(al, bh, acc, 0, 0, 0);
  }

  // C/D: col = lane&31, row = (r&3) + 8*(r>>2) + 4*(lane>>5)   [m74/m101]
  float* Sp = Spart + (size_t)blk * (NN * NN);
  const int j = j0 + ln;
  if (j < NN) {
    #pragma unroll
    for (int r = 0; r < 16; ++r) {
      const int i = i0 + (r & 3) + 8 * (r >> 2) + 4 * g;
      if (i < NN) Sp[i * NN + j] = acc[r];
    }
  }
}

// ---------------- Kernel 2: S[b] = sum_s Spart, zero-padded 64x52 -----------
__global__ __launch_bounds__(256) void sred_kernel(
    const float* __restrict__ Spart, float* __restrict__ Sg, int split) {
  const int b = blockIdx.x;
  const int t = threadIdx.x;
  for (int e = t; e < 64 * NPAD; e += 256) {
    const int m = e / NPAD, n = e - m * NPAD;
    float v = 0.f;
    if (m < NN && n < NN) {
      for (int s = 0; s < split; ++s)
        v += Spart[(size_t)(b * split + s) * (NN * NN) + m * NN + n];
    }
    Sg[(size_t)b * (64 * NPAD) + e] = v;
  }
}

// ---------------- Kernel 3: out[64-row tile] = q @ S + v  (MFMA) ------------
// A = q rows (LDS transpose, conflict-free), B = S (coalesced global, L2-hot).
__global__ __launch_bounds__(256) void qs_kernel(
    const float* __restrict__ Qg, const float* __restrict__ Vg,
    const float* __restrict__ Sg, float* __restrict__ Og) {
  const int blk  = blockIdx.x;            // 2048 = 128 batches x 16 row-tiles
  const int b    = blk >> 4;
  const int rt   = blk & 15;
  const int tid  = threadIdx.x;
  const int wv   = tid >> 6;
  const int lane = tid & 63;
  const int g    = lane >> 5;
  const int ln   = lane & 31;
  const int i0   = (wv >> 1) * 32;
  const int j0   = (wv & 1)  * 32;

  __shared__ float Qt[64 * LDQ];          // 16.6 KB -> 8 blocks/CU possible

  const size_t qbase = ((size_t)b * CH + (size_t)rt * 64) * NN;

  // stage q transposed: Qt[m][r] = q[r0+r][m]; coalesced reads, conflict-free writes
  for (int idx = tid; idx < 64 * NN; idx += 256) {
    const int r = idx / NN, m = idx - r * NN;
    Qt[m * LDQ + r] = Qg[qbase + idx];
  }
  for (int idx = tid; idx < (64 - NN) * LDQ; idx += 256)   // zero pad m=49..63
    Qt[NN * LDQ + idx] = 0.f;
  __syncthreads();

  const float* Sb = Sg + (size_t)b * (64 * NPAD);
  const int colB = min(j0 + ln, NN - 1);   // clamp: stay in-bounds, junk discarded

  f32x16 acc;
  #pragma unroll
  for (int r = 0; r < 16; ++r) acc[r] = 0.f;

  #pragma unroll
  for (int kc = 0; kc < 4; ++kc) {
    const int m0 = kc * 16 + g * 8;
    float qx[8], sx[8];
    #pragma unroll
    for (int e = 0; e < 8; ++e) {
      qx[e] = Qt[(m0 + e) * LDQ + i0 + ln];      // lane-consecutive LDS
      sx[e] = Sb[(m0 + e) * NPAD + colB];        // coalesced global, L2-hot
    }
    bf16x8 ah, al, bh, bl;
    #pragma unroll
    for (int e = 0; e < 8; ++e) {
      const short qh = bf16_trunc(qx[e]);
      const short sh = bf16_trunc(sx[e]);
      ah[e] = qh;  al[e] = bf16_trunc(qx[e] - bf16_f32(qh));
      bh[e] = sh;  bl[e] = bf16_trunc(sx[e] - bf16_f32(sh));
    }
    acc = __builtin_amdgcn_mfma_f32_32x32x16_bf16(ah, bh, acc, 0, 0, 0);
    acc = __builtin_amdgcn_mfma_f32_32x32x16_bf16(ah, bl, acc, 0, 0, 0);
    acc = __builtin_amdgcn_mfma_f32_32x32x16_bf16(al, bh, acc, 0, 0, 0);
  }

  // store: all 64 rows valid (rows = channels); guard only col j < 49
  const int j = j0 + ln;
  if (j < NN) {
    #pragma unroll
    for (int r = 0; r < 16; ++r) {
      const int i = i0 + (r & 3) + 8 * (r >> 2) + 4 * g;
      const size_t off = qbase + (size_t)i * NN + j;
      Og[off] = acc[r] + Vg[off];                // coalesced per r
    }
  }
}

extern "C" void kernel_launch(void* const* d_in, const int* in_sizes, int n_in,
                              void* d_out, int out_size, void* d_ws, size_t ws_size,
                              hipStream_t stream) {
  (void)in_sizes; (void)n_in; (void)out_size;
  const float* v1 = (const float*)d_in[0];
  const float* q1 = (const float*)d_in[1];
  const float* k1 = (const float*)d_in[2];
  float* out = (float*)d_out;

  int split = 8;                                  // 9.8MB + 1.7MB workspace
  while (split > 1 &&
         ((size_t)BATCH * split * NN * NN + (size_t)BATCH * 64 * NPAD) * 4 > ws_size)
    split >>= 1;
  const int nchunks = CH / (split * 16);

  float* spart = (float*)d_ws;
  float* sg    = spart + (size_t)BATCH * split * NN * NN;

  ktv_kernel<<<dim3(BATCH * split), dim3(256), 0, stream>>>(k1, v1, spart, split, nchunks);
  sred_kernel<<<dim3(BATCH), dim3(256), 0, stream>>>(spart, sg, split);
  qs_kernel<<<dim3(BATCH * 16), dim3(256), 0, stream>>>(q1, v1, sg, out);
}